// Round 2
// baseline (269.025 us; speedup 1.0000x reference)
//
#include <hip/hip_runtime.h>
#include <math.h>

#define NDIM   32
#define NPAIRS 528        // 32*33/2
#define NTRIP  5984       // C(34,3)
#define NCOLS  (1 + NDIM + NPAIRS + NTRIP + NDIM)   // 6577
#define ONE_IDX 64        // encodes the constant 1.0

// Packed index table: column c of the library is  g(i)*g(j)*g(k)  where
//   g(i) = z[i]        for i in [0,32)
//   g(i) = sin(z[i-32]) for i in [32,64)
//   g(64) = 1.0f
// (i, j, k) packed as three 7-bit fields of a u32.
struct Tbl { unsigned int v[NCOLS]; };

constexpr Tbl make_tbl() {
    Tbl t{};
    int c = 0;
    const unsigned ONE = ONE_IDX;
    // ones
    t.v[c++] = ONE | (ONE << 7) | (ONE << 14);
    // z
    for (unsigned i = 0; i < NDIM; ++i)
        t.v[c++] = i | (ONE << 7) | (ONE << 14);
    // pairs: np.triu_indices order (i ascending, j from i..31)
    for (unsigned i = 0; i < NDIM; ++i)
        for (unsigned j = i; j < NDIM; ++j)
            t.v[c++] = i | (j << 7) | (ONE << 14);
    // triples: a<=b<=c, a-major
    for (unsigned a = 0; a < NDIM; ++a)
        for (unsigned b = a; b < NDIM; ++b)
            for (unsigned k = b; k < NDIM; ++k)
                t.v[c++] = a | (b << 7) | (k << 14);
    // sin(z)
    for (unsigned i = 0; i < NDIM; ++i)
        t.v[c++] = (NDIM + i) | (ONE << 7) | (ONE << 14);
    return t;
}

__device__ __constant__ Tbl TBL = make_tbl();

__device__ __forceinline__ float fetch(const float* __restrict__ zr, unsigned i) {
    if (i < 32u)  return zr[i];          // z value (L1 hit)
    if (i < 64u)  return sinf(zr[i - 32u]); // sin column (rare: 32/6577 cols)
    return 1.0f;                          // the constant
}

__global__ __launch_bounds__(256)
void sindy_flat_kernel(const float* __restrict__ z, float* __restrict__ out,
                       int total4) {
    const int stride = gridDim.x * 256;
    for (int idx = blockIdx.x * 256 + threadIdx.x; idx < total4; idx += stride) {
        const unsigned f = (unsigned)idx * 4u;
        unsigned row = f / NCOLS;          // compiler magic-div (const divisor)
        unsigned col = f - row * NCOLS;
        const float* zr = z + row * NDIM;

        float v[4];
#pragma unroll
        for (int j = 0; j < 4; ++j) {
            const unsigned e = TBL.v[col];
            v[j] = fetch(zr, e & 127u) * fetch(zr, (e >> 7) & 127u)
                 * fetch(zr, (e >> 14) & 127u);
            ++col;
            if (col == NCOLS) { col = 0; zr += NDIM; }  // row crossing (rare)
        }
        // f % 4 == 0 and base is allocation-aligned -> aligned 16B store
        *reinterpret_cast<float4*>(out + f) = make_float4(v[0], v[1], v[2], v[3]);
    }
}

extern "C" void kernel_launch(void* const* d_in, const int* in_sizes, int n_in,
                              void* d_out, int out_size, void* d_ws, size_t ws_size,
                              hipStream_t stream) {
    const float* z = (const float*)d_in[0];
    float* out     = (float*)d_out;
    const int rows   = in_sizes[0] / NDIM;        // 8192
    const int total  = rows * NCOLS;              // 53,878,784 (divisible by 4)
    const int total4 = total / 4;
    const int blocks = 2048;                      // 32 waves/CU, grid-stride
    sindy_flat_kernel<<<blocks, 256, 0, stream>>>(z, out, total4);
}

// Round 3
// 255.604 us; speedup vs baseline: 1.0525x; 1.0525x over previous
//
#include <hip/hip_runtime.h>
#include <math.h>

#define NDIM   32
#define NPAIRS 528        // 32*33/2
#define NTRIP  5984       // C(34,3)
#define NCOLS  (1 + NDIM + NPAIRS + NTRIP + NDIM)   // 6577
#define ULEN   593        // 528 pair-products + 32 z + 32 sin + 1 one
#define ZOFF   528
#define SOFF   560
#define ONEOFF 592

// Every library column c is u[pi]*u[qi] where per-row
//   u[0..527]   = z[a]*z[b] for (a,b) in triu order
//   u[528..559] = z[i]
//   u[560..591] = sin(z[i])
//   u[592]      = 1.0f
// TBL packs (pi, qi) as two 10-bit fields.
struct Tbl  { unsigned v[NCOLS]; };
struct PTbl { unsigned v[NPAIRS]; };

constexpr unsigned pidx(int a, int b) {
    return (unsigned)(a * NDIM - a * (a - 1) / 2 + (b - a));
}

constexpr Tbl make_tbl() {
    Tbl t{}; int c = 0;
    t.v[c++] = ONEOFF | (ONEOFF << 10);                        // ones
    for (int i = 0; i < NDIM; ++i)                             // z
        t.v[c++] = (ZOFF + i) | (ONEOFF << 10);
    for (int i = 0; i < NDIM; ++i)                             // pairs (triu order)
        for (int j = i; j < NDIM; ++j)
            t.v[c++] = pidx(i, j) | (ONEOFF << 10);
    for (int a = 0; a < NDIM; ++a)                             // triples a<=b<=k
        for (int b = a; b < NDIM; ++b)
            for (int k = b; k < NDIM; ++k)
                t.v[c++] = pidx(a, b) | ((unsigned)(ZOFF + k) << 10);
    for (int i = 0; i < NDIM; ++i)                             // sin(z)
        t.v[c++] = (SOFF + i) | (ONEOFF << 10);
    return t;
}

constexpr PTbl make_ptbl() {
    PTbl t{}; int c = 0;
    for (int i = 0; i < NDIM; ++i)
        for (int j = i; j < NDIM; ++j)
            t.v[c++] = (unsigned)i | ((unsigned)j << 8);
    return t;
}

__device__ __constant__ Tbl  TBL  = make_tbl();
__device__ __constant__ PTbl PTBL = make_ptbl();

__global__ __launch_bounds__(256)
void sindy_kernel(const float* __restrict__ z, float* __restrict__ out) {
    __shared__ float u[4 * ULEN];
    const int tid  = threadIdx.x;
    const int row0 = blockIdx.x * 4;

    // Stage z, sin(z), 1.0 for the block's 4 rows.
    if (tid < 128) {
        const int r = tid >> 5, i = tid & 31;
        const float v = z[(row0 + r) * NDIM + i];
        u[r * ULEN + ZOFF + i] = v;
        u[r * ULEN + SOFF + i] = sinf(v);
        if (i == 0) u[r * ULEN + ONEOFF] = 1.0f;
    }
    __syncthreads();

    // Stage the 4x528 pair products (reads the z section just written).
#pragma unroll
    for (int r = 0; r < 4; ++r) {
        const float* ur = u + r * ULEN;
        for (int p = tid; p < NPAIRS; p += 256) {
            const unsigned e = PTBL.v[p];
            u[r * ULEN + p] = ur[ZOFF + (e & 255u)] * ur[ZOFF + (e >> 8)];
        }
    }
    __syncthreads();

    // 6577 float4s per block (4 rows x 6577 cols, span is 16B-aligned).
    float* const outb = out + (long long)row0 * NCOLS;
    for (int t = tid; t < NCOLS; t += 256) {
        const int flat = t * 4;
        int r   = flat / NCOLS;            // const divisor -> magic mul
        int col = flat - r * NCOLS;
        const float* ur = u + r * ULEN;
        float v[4];
#pragma unroll
        for (int j = 0; j < 4; ++j) {
            const unsigned e = TBL.v[col];
            v[j] = ur[e & 1023u] * ur[(e >> 10) & 1023u];
            if (++col == NCOLS) { col = 0; ur += ULEN; }   // row crossing
        }
        *reinterpret_cast<float4*>(outb + flat) = make_float4(v[0], v[1], v[2], v[3]);
    }
}

extern "C" void kernel_launch(void* const* d_in, const int* in_sizes, int n_in,
                              void* d_out, int out_size, void* d_ws, size_t ws_size,
                              hipStream_t stream) {
    const float* z = (const float*)d_in[0];
    float* out     = (float*)d_out;
    const int rows   = in_sizes[0] / NDIM;   // 8192
    const int blocks = rows / 4;             // 2048
    sindy_kernel<<<blocks, 256, 0, stream>>>(z, out);
}

// Round 4
// 211.332 us; speedup vs baseline: 1.2730x; 1.2095x over previous
//
#include <hip/hip_runtime.h>
#include <math.h>

#define NDIM   32
#define NPAIRS 528          // 32*33/2
#define NCOLS  6577         // 1 + 32 + 528 + 5984 + 32
#define PAD    608          // padded floats per LDS row (593 used)
#define ZOFF   528
#define SOFF   560
#define ONEOFF 592
#define RPB    8            // rows per block
#define NSLOT  26           // ceil(NCOLS/256)

// Each library column c is u[pi]*u[qi] where, per row,
//   u[0..527]   = z[a]*z[b]   (triu pair products)
//   u[528..559] = z[i]
//   u[560..591] = sin(z[i])
//   u[592]      = 1.0f
// TBL.v[c] = pi | (qi << 12).
struct Tbl  { unsigned v[NCOLS]; };
struct PTbl { unsigned v[NPAIRS]; };

constexpr unsigned pidx(int a, int b) {
    return (unsigned)(a * NDIM - a * (a - 1) / 2 + (b - a));
}

constexpr Tbl make_tbl() {
    Tbl t{}; int c = 0;
    t.v[c++] = ONEOFF | (ONEOFF << 12);                       // ones
    for (int i = 0; i < NDIM; ++i)                            // z
        t.v[c++] = (unsigned)(ZOFF + i) | (ONEOFF << 12);
    for (int i = 0; i < NDIM; ++i)                            // pairs (triu order)
        for (int j = i; j < NDIM; ++j)
            t.v[c++] = pidx(i, j) | (ONEOFF << 12);
    for (int a = 0; a < NDIM; ++a)                            // triples a<=b<=k
        for (int b = a; b < NDIM; ++b)
            for (int k = b; k < NDIM; ++k)
                t.v[c++] = pidx(a, b) | ((unsigned)(ZOFF + k) << 12);
    for (int i = 0; i < NDIM; ++i)                            // sin(z)
        t.v[c++] = (unsigned)(SOFF + i) | (ONEOFF << 12);
    return t;
}

constexpr PTbl make_ptbl() {
    PTbl t{}; int c = 0;
    for (int i = 0; i < NDIM; ++i)
        for (int j = i; j < NDIM; ++j)
            t.v[c++] = (unsigned)i | ((unsigned)j << 8);
    return t;
}

__device__ __constant__ Tbl  TBL  = make_tbl();
__device__ __constant__ PTbl PTBL = make_ptbl();

__global__ __launch_bounds__(256)
void sindy_kernel(const float* __restrict__ z, float* __restrict__ out) {
    __shared__ float u[RPB * PAD];
    const int tid  = threadIdx.x;
    const int row0 = blockIdx.x * RPB;

    // ---- Preload this thread's 26 operand-index pairs into registers. ----
    unsigned idx[NSLOT];
#pragma unroll
    for (int j = 0; j < NSLOT; ++j) {
        const int c = tid + 256 * j;
        idx[j] = TBL.v[c < NCOLS ? c : 0];
    }

    // ---- Stage z, sin(z), 1.0 for RPB rows (one coalesced KB of z). ----
    {
        const int r = tid >> 5, d = tid & 31;     // 256 threads = 8 rows x 32
        const float v = z[(row0 + r) * NDIM + d];
        u[r * PAD + ZOFF + d] = v;
        u[r * PAD + SOFF + d] = sinf(v);
        if (tid < RPB) u[tid * PAD + ONEOFF] = 1.0f;
    }
    __syncthreads();

    // ---- Stage the RPB x 528 pair products. ----
    for (int p = tid; p < RPB * NPAIRS; p += 256) {
        const int r = p / NPAIRS;                 // const divisor -> magic mul
        const int q = p - r * NPAIRS;
        const unsigned e = PTBL.v[q];
        const float* ur = u + r * PAD + ZOFF;
        u[r * PAD + q] = ur[e & 255u] * ur[e >> 8];
    }
    __syncthreads();

    // ---- Barrier-free store sweep: 8 rows x 26 coalesced scalar stores. ----
    for (int r = 0; r < RPB; ++r) {
        const float* __restrict__ ur = u + r * PAD;
        float* __restrict__ ro = out + (size_t)(row0 + r) * NCOLS;
#pragma unroll
        for (int j = 0; j < NSLOT; ++j) {
            const int c = tid + 256 * j;
            if (j < NSLOT - 1 || c < NCOLS) {
                const unsigned e = idx[j];
                ro[c] = ur[e & 4095u] * ur[e >> 12];
            }
        }
    }
}

extern "C" void kernel_launch(void* const* d_in, const int* in_sizes, int n_in,
                              void* d_out, int out_size, void* d_ws, size_t ws_size,
                              hipStream_t stream) {
    const float* z = (const float*)d_in[0];
    float* out     = (float*)d_out;
    const int rows   = in_sizes[0] / NDIM;   // 8192
    const int blocks = rows / RPB;           // 1024
    sindy_kernel<<<blocks, 256, 0, stream>>>(z, out);
}